// Round 1
// baseline (3504.391 us; speedup 1.0000x reference)
//
#include <hip/hip_runtime.h>
#include <hip/hip_bf16.h>

typedef __bf16 bf16;
typedef __attribute__((ext_vector_type(8))) __bf16 bf16x8;
typedef __attribute__((ext_vector_type(4))) float f32x4;

constexpr int BATCH = 8192, NN = 49, ND = 26, NOUT = 1274, FD = 1280;
constexpr int HID = 256, NE = 361, HEADS = 4;
constexpr int KT_X = 40;   // 1280/32 K-tiles (transform)
constexpr int MT_X = 512;  // 8192/16 M-tiles
constexpr int NT_X = 80;   // 1280/16 N-tiles (1274 padded to 1280)

// ---- workspace layout (bytes) ----
constexpr size_t OFF_XPACK = 0;
constexpr size_t SZ_XPACK  = (size_t)MT_X * KT_X * 64 * 8 * 2;   // 20,971,520
constexpr size_t OFF_WPACK = OFF_XPACK + SZ_XPACK;
constexpr size_t SZ_WPACK  = (size_t)NT_X * KT_X * 64 * 8 * 2;   // 3,276,800
constexpr size_t OFF_B1    = OFF_WPACK + SZ_WPACK;
constexpr size_t SZ_B1     = (size_t)32 * 1 * 64 * 8 * 2;        // 32 KB
constexpr size_t OFF_B2    = OFF_B1 + SZ_B1;
constexpr size_t SZ_B2     = (size_t)32 * 8 * 64 * 8 * 2;        // 256 KB
constexpr size_t OFF_NODE  = OFF_B2 + SZ_B2;
constexpr size_t SZ_NODE   = (size_t)BATCH * NOUT * 4;           // 41.7 MB
constexpr size_t OFF_CSR   = OFF_NODE + SZ_NODE;                 // 772 ints

// ============ K0a: pack x [8192][1280] f32 -> A-fragments bf16 ============
// frag layout for mfma_16x16x32_bf16 A: row = lane&15, k = (lane>>4)*8 + j
__global__ __launch_bounds__(256) void k_pack_x(const float* __restrict__ x,
                                                bf16* __restrict__ xp) {
    int g = blockIdx.x * 256 + threadIdx.x;
    int lane = g & 63, frag = g >> 6;          // frag < 512*40
    int mt = frag / KT_X, kt = frag - mt * KT_X;
    int row = mt * 16 + (lane & 15);
    int k0  = kt * 32 + (lane >> 4) * 8;
    const float* src = x + (size_t)row * FD + k0;
    bf16x8 v;
#pragma unroll
    for (int j = 0; j < 8; ++j) v[j] = (bf16)src[j];
    *(bf16x8*)(xp + ((size_t)frag * 64 + lane) * 8) = v;
}

// ============ K0b: pack transform_w [1280][1274] -> B-fragments ============
// B frag: col(n) = lane&15, k = (lane>>4)*8 + j. Pad n>=1274 with 0.
__global__ __launch_bounds__(256) void k_pack_w(const float* __restrict__ w,
                                                bf16* __restrict__ wp) {
    int g = blockIdx.x * 256 + threadIdx.x;
    int lane = g & 63, frag = g >> 6;          // frag < 80*40
    int nt = frag / KT_X, kt = frag - nt * KT_X;
    int col = nt * 16 + (lane & 15);
    int k0  = kt * 32 + (lane >> 4) * 8;
    bf16x8 v;
#pragma unroll
    for (int j = 0; j < 8; ++j)
        v[j] = (col < NOUT) ? (bf16)w[(size_t)(k0 + j) * NOUT + col] : (bf16)0.f;
    *(bf16x8*)(wp + ((size_t)frag * 64 + lane) * 8) = v;
}

// ============ K0c: pack g1 (wl|wr) [32k x 512n] -> fragments ============
__global__ __launch_bounds__(256) void k_pack_g1(const float* __restrict__ wl,
                                                 const float* __restrict__ wr,
                                                 bf16* __restrict__ bp) {
    int g = blockIdx.x * 256 + threadIdx.x;    // < 32*64
    int lane = g & 63, nt = g >> 6;            // nt < 32
    int n  = nt * 16 + (lane & 15);
    int k0 = (lane >> 4) * 8;
    bf16x8 v;
#pragma unroll
    for (int j = 0; j < 8; ++j) {
        int k = k0 + j;
        float f = 0.f;
        if (k < ND) f = (n < HID) ? wl[k * HID + n] : wr[k * HID + (n - HID)];
        v[j] = (bf16)f;
    }
    *(bf16x8*)(bp + ((size_t)nt * 64 + lane) * 8) = v;
}

// ============ K0d: pack g2 (wl|wr) [256k x 512n] -> fragments ============
__global__ __launch_bounds__(256) void k_pack_g2(const float* __restrict__ wl,
                                                 const float* __restrict__ wr,
                                                 bf16* __restrict__ bp) {
    int g = blockIdx.x * 256 + threadIdx.x;    // < 256*64
    int lane = g & 63, frag = g >> 6;          // frag = nt*8+kt < 256
    int nt = frag >> 3, kt = frag & 7;
    int n  = nt * 16 + (lane & 15);
    int k0 = kt * 32 + (lane >> 4) * 8;
    bf16x8 v;
#pragma unroll
    for (int j = 0; j < 8; ++j) {
        int k = k0 + j;
        float f = (n < HID) ? wl[k * HID + n] : wr[k * HID + (n - HID)];
        v[j] = (bf16)f;
    }
    *(bf16x8*)(bp + ((size_t)frag * 64 + lane) * 8) = v;
}

// ============ K0e: build in-edge CSR (tiny, single thread) ============
__global__ void k_csr(const int* __restrict__ ei, int* __restrict__ csr) {
    if (threadIdx.x != 0 || blockIdx.x != 0) return;
    int cnt[NN];
    for (int n = 0; n < NN; ++n) cnt[n] = 0;
    for (int e = 0; e < NE; ++e) cnt[ei[NE + e]]++;
    csr[0] = 0;
    for (int n = 0; n < NN; ++n) csr[n + 1] = csr[n] + cnt[n];
    int pos[NN];
    for (int n = 0; n < NN; ++n) pos[n] = csr[n];
    for (int e = 0; e < NE; ++e) {
        int d = ei[NE + e];
        csr[50 + pos[d]]      = e;        // in-edge id
        csr[50 + NE + pos[d]] = ei[e];    // in-edge src
        pos[d]++;
    }
}

// ============ K1: transform GEMM (LDS-free, pre-packed frags) ============
__global__ __launch_bounds__(256) void k_gemm_node(const bf16* __restrict__ xp,
                                                   const bf16* __restrict__ wp,
                                                   const float* __restrict__ tb,
                                                   float* __restrict__ node) {
    int tid = threadIdx.x, lane = tid & 63, w = tid >> 6;
    int mtb = blockIdx.x * 8 + (w >> 1) * 4;
    int ntb = blockIdx.y * 8 + (w & 1) * 4;
    f32x4 acc[4][4] = {};
    for (int kt = 0; kt < KT_X; ++kt) {
        bf16x8 a[4], b[4];
#pragma unroll
        for (int i = 0; i < 4; ++i)
            a[i] = *(const bf16x8*)(xp + (((size_t)(mtb + i) * KT_X + kt) * 64 + lane) * 8);
#pragma unroll
        for (int j = 0; j < 4; ++j)
            b[j] = *(const bf16x8*)(wp + (((size_t)(ntb + j) * KT_X + kt) * 64 + lane) * 8);
#pragma unroll
        for (int i = 0; i < 4; ++i)
#pragma unroll
            for (int j = 0; j < 4; ++j)
                acc[i][j] = __builtin_amdgcn_mfma_f32_16x16x32_bf16(a[i], b[j], acc[i][j], 0, 0, 0);
    }
    int c0 = lane & 15, r0 = (lane >> 4) * 4;
#pragma unroll
    for (int j = 0; j < 4; ++j) {
        int col = (ntb + j) * 16 + c0;
        if (col >= NOUT) continue;
        float bias = tb[col];
#pragma unroll
        for (int i = 0; i < 4; ++i) {
            int rowb = (mtb + i) * 16 + r0;
#pragma unroll
            for (int r = 0; r < 4; ++r)
                node[(size_t)(rowb + r) * NOUT + col] = acc[i][j][r] + bias;
        }
    }
}

// ============ K2: fused per-graph GAT (1 WG = 1 graph, 512 thr) ============
static __device__ __forceinline__ float waveReduceSum(float v) {
#pragma unroll
    for (int m = 32; m > 0; m >>= 1) v += __shfl_xor(v, m, 64);
    return v;
}

__global__ __launch_bounds__(512, 1) void k_gat(
    const float* __restrict__ nodeG, const bf16* __restrict__ b1p, const bf16* __restrict__ b2p,
    const float* __restrict__ att1, const float* __restrict__ att2,
    const float* __restrict__ g1b, const float* __restrict__ g2b,
    const float* __restrict__ fcw, const float* __restrict__ fcb,
    const int* __restrict__ ei, const int* __restrict__ csr,
    float* __restrict__ out)
{
    __shared__ __align__(16) bf16 node_b[64 * 32];    // swizzled A for layer1
    __shared__ __align__(16) bf16 xlr[64 * 512];      // xl|xr (layer1 then layer2)
    __shared__ __align__(16) bf16 h1s[64 * 256];      // swizzled A for layer2
    __shared__ float node_f[NN * ND];
    __shared__ float scores[NE * HEADS];              // reused (NE) in layer2
    __shared__ float smax[NN * HEADS], srden[NN * HEADS];
    __shared__ float att1s[256], att2s[256], b1s[256], b2s[256];
    __shared__ int   srcs[NE], dsts[NE], ieOff[64], ieIdS[NE], ieSrcS[NE];
    __shared__ float pooled[288];

    const int b = blockIdx.x, tid = threadIdx.x;
    const int w = tid >> 6, lane = tid & 63;
    const float* nrow = nodeG + (size_t)b * NOUT;

    // ---- P0: stage constants + node row ----
    for (int i = tid; i < 256; i += 512) {
        att1s[i] = att1[i]; att2s[i] = att2[i]; b1s[i] = g1b[i]; b2s[i] = g2b[i];
    }
    for (int i = tid; i < NE; i += 512) {
        srcs[i] = ei[i]; dsts[i] = ei[NE + i];
        ieIdS[i] = csr[50 + i]; ieSrcS[i] = csr[50 + NE + i];
    }
    if (tid < 50) ieOff[tid] = csr[tid];
    for (int i = tid; i < NN * ND; i += 512) node_f[i] = nrow[i];
    for (int i = tid; i < 64 * 32; i += 512) {
        int n = i >> 5, d = i & 31;
        float v = (n < NN && d < ND) ? nrow[n * ND + d] : 0.f;
        int byte = ((n * 32 + d) * 2) ^ ((n & 7) << 4);  // swizzle
        *(bf16*)((char*)node_b + byte) = (bf16)v;
    }
    __syncthreads();

    // ---- P1: layer1 GEMM  [64,32]bf16 @ [32,512] -> xlr bf16 ----
    {
        bf16x8 a[4];
#pragma unroll
        for (int mt = 0; mt < 4; ++mt) {
            int row = mt * 16 + (lane & 15);
            int byte = (row * 64 + (lane >> 4) * 16) ^ ((row & 7) << 4);
            a[mt] = *(const bf16x8*)((const char*)node_b + byte);
        }
#pragma unroll
        for (int q = 0; q < 4; ++q) {
            int nt = w * 4 + q;
            bf16x8 bb = *(const bf16x8*)(b1p + ((size_t)nt * 64 + lane) * 8);
            int col = nt * 16 + (lane & 15);
#pragma unroll
            for (int mt = 0; mt < 4; ++mt) {
                f32x4 z = {0.f, 0.f, 0.f, 0.f};
                f32x4 acc = __builtin_amdgcn_mfma_f32_16x16x32_bf16(a[mt], bb, z, 0, 0, 0);
                int rw = mt * 16 + ((lane >> 4) << 2);
#pragma unroll
                for (int r = 0; r < 4; ++r) xlr[(rw + r) * 512 + col] = (bf16)acc[r];
            }
        }
    }
    __syncthreads();

    // ---- P2a: layer1 edge scores (wave-cooperative, 64-lane reduce) ----
    for (int e = w; e < NE; e += 8) {
        int s = srcs[e], d = dsts[e];
        const bf16* xlR = xlr + s * 512;
        const bf16* xrR = xlr + d * 512 + 256;
        float p[4];
#pragma unroll
        for (int h = 0; h < 4; ++h) {
            int c = h * 64 + lane;
            float v = (float)xlR[c] + (float)xrR[c];
            v = v > 0.f ? v : 0.2f * v;
            p[h] = att1s[c] * v;
        }
#pragma unroll
        for (int h = 0; h < 4; ++h) {
            float v = waveReduceSum(p[h]);
            if (lane == 0) scores[e * 4 + h] = v;
        }
    }
    __syncthreads();
    // ---- P2b: per-(node,head) softmax stats ----
    for (int it = tid; it < NN * HEADS; it += 512) {
        int n = it >> 2, h = it & 3;
        float m = -1e30f;
        for (int j = ieOff[n]; j < ieOff[n + 1]; ++j) m = fmaxf(m, scores[ieIdS[j] * 4 + h]);
        float den = 0.f;
        for (int j = ieOff[n]; j < ieOff[n + 1]; ++j) den += expf(scores[ieIdS[j] * 4 + h] - m);
        smax[it] = m; srden[it] = 1.f / den;
    }
    __syncthreads();
    for (int it = tid; it < NE * HEADS; it += 512) {
        int e = it >> 2, h = it & 3, n = dsts[e];
        scores[it] = expf(scores[it] - smax[n * 4 + h]) * srden[n * 4 + h];
    }
    __syncthreads();
    // ---- P2c: aggregate + bias + ELU -> h1 (swizzled bf16) ----
    for (int it = tid; it < NN * HID; it += 512) {
        int n = it >> 8, ch = it & 255;
        float acc = 0.f;
        int j0 = ieOff[n], j1 = ieOff[n + 1], hh = ch >> 6;
        for (int j = j0; j < j1; ++j)
            acc += scores[ieIdS[j] * 4 + hh] * (float)xlr[ieSrcS[j] * 512 + ch];
        float v = acc + b1s[ch];
        v = v > 0.f ? v : expm1f(v);
        int byte = ((n * 256 + ch) * 2) ^ ((n & 7) << 4);
        *(bf16*)((char*)h1s + byte) = (bf16)v;
    }
    __syncthreads();

    // ---- P3: layer2 GEMM  [64,256]bf16 @ [256,512] -> xlr bf16 ----
    {
        bf16x8 a[4][8];
#pragma unroll
        for (int mt = 0; mt < 4; ++mt) {
            int row = mt * 16 + (lane & 15);
#pragma unroll
            for (int kt = 0; kt < 8; ++kt) {
                int byte = (row * 512 + kt * 64 + (lane >> 4) * 16) ^ ((row & 7) << 4);
                a[mt][kt] = *(const bf16x8*)((const char*)h1s + byte);
            }
        }
#pragma unroll
        for (int q = 0; q < 4; ++q) {
            int nt = w * 4 + q;
            f32x4 acc[4] = {};
#pragma unroll
            for (int kt = 0; kt < 8; ++kt) {
                bf16x8 bb = *(const bf16x8*)(b2p + (((size_t)nt * 8 + kt) * 64 + lane) * 8);
#pragma unroll
                for (int mt = 0; mt < 4; ++mt)
                    acc[mt] = __builtin_amdgcn_mfma_f32_16x16x32_bf16(a[mt][kt], bb, acc[mt], 0, 0, 0);
            }
            int col = nt * 16 + (lane & 15);
#pragma unroll
            for (int mt = 0; mt < 4; ++mt) {
                int rw = mt * 16 + ((lane >> 4) << 2);
#pragma unroll
                for (int r = 0; r < 4; ++r) xlr[(rw + r) * 512 + col] = (bf16)acc[mt][r];
            }
        }
    }
    __syncthreads();

    // ---- P4a: layer2 edge scores ----
    for (int e = w; e < NE; e += 8) {
        int s = srcs[e], d = dsts[e];
        float p = 0.f;
#pragma unroll
        for (int k = 0; k < 4; ++k) {
            int c = k * 64 + lane;
            float v = (float)xlr[s * 512 + c] + (float)xlr[d * 512 + 256 + c];
            v = v > 0.f ? v : 0.2f * v;
            p += att2s[c] * v;
        }
        p = waveReduceSum(p);
        if (lane == 0) scores[e] = p;
    }
    __syncthreads();
    // ---- P4b: softmax (1 head) ----
    for (int n = tid; n < NN; n += 512) {
        float m = -1e30f;
        for (int j = ieOff[n]; j < ieOff[n + 1]; ++j) m = fmaxf(m, scores[ieIdS[j]]);
        float den = 0.f;
        for (int j = ieOff[n]; j < ieOff[n + 1]; ++j) den += expf(scores[ieIdS[j]] - m);
        smax[n] = m; srden[n] = 1.f / den;
    }
    __syncthreads();
    for (int e = tid; e < NE; e += 512)
        scores[e] = expf(scores[e] - smax[dsts[e]]) * srden[dsts[e]];
    __syncthreads();

    // ---- P5: pooled = [mean_n node | mean_n g] ; logits ----
    if (tid < ND) {
        float s = 0.f;
        for (int n = 0; n < NN; ++n) s += node_f[n * ND + tid];
        pooled[tid] = s * (1.f / NN);
    } else if (tid >= 32 && tid < 32 + HID) {
        int ch = tid - 32;
        float s = 0.f;
        for (int e = 0; e < NE; ++e)
            s += scores[e] * (float)xlr[srcs[e] * 512 + ch];
        pooled[ND + ch] = s * (1.f / NN) + b2s[ch];
    }
    __syncthreads();
    if (tid < 5) {
        float acc = fcb[tid];
        for (int d = 0; d < ND + HID; ++d) acc += pooled[d] * fcw[d * 5 + tid];
        out[(size_t)b * 5 + tid] = acc;
    }
}

// ============ launch ============
extern "C" void kernel_launch(void* const* d_in, const int* in_sizes, int n_in,
                              void* d_out, int out_size, void* d_ws, size_t ws_size,
                              hipStream_t stream) {
    const float* x   = (const float*)d_in[0];
    const float* tw  = (const float*)d_in[1];
    const float* tb  = (const float*)d_in[2];
    const float* wl1 = (const float*)d_in[3];
    const float* wr1 = (const float*)d_in[4];
    const float* at1 = (const float*)d_in[5];
    const float* b1  = (const float*)d_in[6];
    const float* wl2 = (const float*)d_in[7];
    const float* wr2 = (const float*)d_in[8];
    const float* at2 = (const float*)d_in[9];
    const float* b2  = (const float*)d_in[10];
    const float* fcw = (const float*)d_in[11];
    const float* fcb = (const float*)d_in[12];
    const int*   ei  = (const int*)d_in[13];
    float* out = (float*)d_out;

    char* ws = (char*)d_ws;
    bf16* xp   = (bf16*)(ws + OFF_XPACK);
    bf16* wp   = (bf16*)(ws + OFF_WPACK);
    bf16* b1p  = (bf16*)(ws + OFF_B1);
    bf16* b2p  = (bf16*)(ws + OFF_B2);
    float* node = (float*)(ws + OFF_NODE);
    int*  csr  = (int*)(ws + OFF_CSR);

    k_pack_x<<<dim3(MT_X * KT_X * 64 / 256), dim3(256), 0, stream>>>(x, xp);
    k_pack_w<<<dim3(NT_X * KT_X * 64 / 256), dim3(256), 0, stream>>>(tw, wp);
    k_pack_g1<<<dim3(8), dim3(256), 0, stream>>>(wl1, wr1, b1p);
    k_pack_g2<<<dim3(64), dim3(256), 0, stream>>>(wl2, wr2, b2p);
    k_csr<<<dim3(1), dim3(64), 0, stream>>>(ei, csr);
    k_gemm_node<<<dim3(64, 10), dim3(256), 0, stream>>>(xp, wp, tb, node);
    k_gat<<<dim3(BATCH), dim3(512), 0, stream>>>(node, b1p, b2p, at1, at2, b1, b2,
                                                 fcw, fcb, ei, csr, out);
}

// Round 2
// 1331.215 us; speedup vs baseline: 2.6325x; 2.6325x over previous
//
#include <hip/hip_runtime.h>
#include <hip/hip_bf16.h>

typedef __bf16 bf16;
typedef __attribute__((ext_vector_type(8))) __bf16 bf16x8;
typedef __attribute__((ext_vector_type(4))) float f32x4;

constexpr int BATCH = 8192, NN = 49, ND = 26, NOUT = 1274, FD = 1280;
constexpr int HID = 256, NE = 361, HEADS = 4;
constexpr int KT_X = 40;   // 1280/32 K-tiles (transform)
constexpr int MT_X = 512;  // 8192/16 M-tiles
constexpr int NT_X = 80;   // 1280/16 N-tiles (1274 padded to 1280)

// ---- workspace layout (bytes) ----
constexpr size_t OFF_XPACK = 0;
constexpr size_t SZ_XPACK  = (size_t)MT_X * KT_X * 512 * 2;      // 20,971,520
constexpr size_t OFF_WPACK = OFF_XPACK + SZ_XPACK;
constexpr size_t SZ_WPACK  = (size_t)NT_X * KT_X * 512 * 2;      // 3,276,800
constexpr size_t OFF_B1    = OFF_WPACK + SZ_WPACK;
constexpr size_t SZ_B1     = (size_t)32 * 512 * 2;               // 32 KB
constexpr size_t OFF_B2    = OFF_B1 + SZ_B1;
constexpr size_t SZ_B2     = (size_t)32 * 8 * 512 * 2;           // 256 KB
constexpr size_t OFF_A1    = OFF_B2 + SZ_B2;
constexpr size_t SZ_A1     = (size_t)(BATCH * NN / 16) * 512 * 2; // 25,690,112
constexpr size_t OFF_PN    = OFF_A1 + SZ_A1;
constexpr size_t SZ_PN     = (size_t)BATCH * ND * 4;             // 851,968
constexpr size_t OFF_CSR   = OFF_PN + SZ_PN;
constexpr size_t SZ_CSR    = 4096;
constexpr size_t OFF_CHUNK = OFF_CSR + SZ_CSR;                   // 51,089,408

// ============ K0a: pack x [8192][1280] f32 -> A-fragments bf16 ============
__global__ __launch_bounds__(256) void k_pack_x(const float* __restrict__ x,
                                                bf16* __restrict__ xp) {
    int g = blockIdx.x * 256 + threadIdx.x;
    int lane = g & 63, frag = g >> 6;
    int mt = frag / KT_X, kt = frag - mt * KT_X;
    int row = mt * 16 + (lane & 15);
    int k0  = kt * 32 + (lane >> 4) * 8;
    const float* src = x + (size_t)row * FD + k0;
    bf16x8 v;
#pragma unroll
    for (int j = 0; j < 8; ++j) v[j] = (bf16)src[j];
    *(bf16x8*)(xp + ((size_t)frag * 64 + lane) * 8) = v;
}

// ============ K0b: pack transform_w [1280][1274] -> B-fragments ============
__global__ __launch_bounds__(256) void k_pack_w(const float* __restrict__ w,
                                                bf16* __restrict__ wp) {
    int g = blockIdx.x * 256 + threadIdx.x;
    int lane = g & 63, frag = g >> 6;
    int nt = frag / KT_X, kt = frag - nt * KT_X;
    int col = nt * 16 + (lane & 15);
    int k0  = kt * 32 + (lane >> 4) * 8;
    bf16x8 v;
#pragma unroll
    for (int j = 0; j < 8; ++j)
        v[j] = (col < NOUT) ? (bf16)w[(size_t)(k0 + j) * NOUT + col] : (bf16)0.f;
    *(bf16x8*)(wp + ((size_t)frag * 64 + lane) * 8) = v;
}

// ============ K0c: pack g1 (wl|wr) [26k pad32 x 512n] -> B-fragments ========
__global__ __launch_bounds__(256) void k_pack_g1(const float* __restrict__ wl,
                                                 const float* __restrict__ wr,
                                                 bf16* __restrict__ bp) {
    int g = blockIdx.x * 256 + threadIdx.x;    // < 32*64
    int lane = g & 63, nt = g >> 6;
    int n  = nt * 16 + (lane & 15);
    int k0 = (lane >> 4) * 8;
    bf16x8 v;
#pragma unroll
    for (int j = 0; j < 8; ++j) {
        int k = k0 + j;
        float f = 0.f;
        if (k < ND) f = (n < HID) ? wl[k * HID + n] : wr[k * HID + (n - HID)];
        v[j] = (bf16)f;
    }
    *(bf16x8*)(bp + ((size_t)nt * 64 + lane) * 8) = v;
}

// ============ K0d: pack g2 (wl|wr) [256k x 512n] -> B-fragments ============
__global__ __launch_bounds__(256) void k_pack_g2(const float* __restrict__ wl,
                                                 const float* __restrict__ wr,
                                                 bf16* __restrict__ bp) {
    int g = blockIdx.x * 256 + threadIdx.x;    // < 256*64
    int lane = g & 63, frag = g >> 6;          // frag = nt*8+kt
    int nt = frag >> 3, kt = frag & 7;
    int n  = nt * 16 + (lane & 15);
    int k0 = kt * 32 + (lane >> 4) * 8;
    bf16x8 v;
#pragma unroll
    for (int j = 0; j < 8; ++j) {
        int k = k0 + j;
        float f = (n < HID) ? wl[k * HID + n] : wr[k * HID + (n - HID)];
        v[j] = (bf16)f;
    }
    *(bf16x8*)(bp + ((size_t)frag * 64 + lane) * 8) = v;
}

// ============ K0e: build in-edge CSR ============
__global__ void k_csr(const int* __restrict__ ei, int* __restrict__ csr) {
    if (threadIdx.x != 0 || blockIdx.x != 0) return;
    int cnt[NN];
    for (int n = 0; n < NN; ++n) cnt[n] = 0;
    for (int e = 0; e < NE; ++e) cnt[ei[NE + e]]++;
    csr[0] = 0;
    for (int n = 0; n < NN; ++n) csr[n + 1] = csr[n] + cnt[n];
    int pos[NN];
    for (int n = 0; n < NN; ++n) pos[n] = csr[n];
    for (int e = 0; e < NE; ++e) {
        int d = ei[NE + e];
        csr[50 + pos[d]]      = e;        // in-edge id
        csr[50 + NE + pos[d]] = ei[e];    // in-edge src
        pos[d]++;
    }
}

// ============ K1: transform GEMM -> A1 fragments (bf16) + pooled-node ======
__global__ __launch_bounds__(256) void k_gemm_node(const bf16* __restrict__ xp,
                                                   const bf16* __restrict__ wp,
                                                   const float* __restrict__ tb,
                                                   bf16* __restrict__ A1,
                                                   float* __restrict__ pooledN) {
    int tid = threadIdx.x, lane = tid & 63, w = tid >> 6;
    int mtb = blockIdx.x * 8 + (w >> 1) * 4;
    int ntb = blockIdx.y * 8 + (w & 1) * 4;
    f32x4 acc[4][4] = {};
    for (int kt = 0; kt < KT_X; ++kt) {
        bf16x8 a[4], b[4];
#pragma unroll
        for (int i = 0; i < 4; ++i)
            a[i] = *(const bf16x8*)(xp + (((size_t)(mtb + i) * KT_X + kt) * 64 + lane) * 8);
#pragma unroll
        for (int j = 0; j < 4; ++j)
            b[j] = *(const bf16x8*)(wp + (((size_t)(ntb + j) * KT_X + kt) * 64 + lane) * 8);
#pragma unroll
        for (int i = 0; i < 4; ++i)
#pragma unroll
            for (int j = 0; j < 4; ++j)
                acc[i][j] = __builtin_amdgcn_mfma_f32_16x16x32_bf16(a[i], b[j], acc[i][j], 0, 0, 0);
    }
    int c0 = lane & 15, r0 = (lane >> 4) * 4;
#pragma unroll
    for (int j = 0; j < 4; ++j) {
        int col = (ntb + j) * 16 + c0;
        if (col >= NOUT) continue;
        float bias = tb[col];
        int n = col / 26, d = col - n * 26;
#pragma unroll
        for (int i = 0; i < 4; ++i) {
            int rowb = (mtb + i) * 16 + r0;
#pragma unroll
            for (int r = 0; r < 4; ++r) {
                int brow = rowb + r;                  // batch index
                float val = acc[i][j][r] + bias;
                int R = brow * NN + n;                // global node row
                A1[(((size_t)(R >> 4)) * 64 + ((d >> 3) << 4) + (R & 15)) * 8 + (d & 7)] = (bf16)val;
                atomicAdd(&pooledN[brow * ND + d], val);
            }
        }
    }
}

// ============ K2: GAT GEMM (pre-packed frags -> swizzled row-major bf16) ===
template<int KT>
__global__ __launch_bounds__(256) void k_gemm_gat(const bf16* __restrict__ Af,
                                                  const bf16* __restrict__ Bf,
                                                  char* __restrict__ xlr) {
    int tid = threadIdx.x, lane = tid & 63, w = tid >> 6;
    int mtb = blockIdx.x * 8 + (w >> 1) * 4;
    int ntb = blockIdx.y * 8 + (w & 1) * 4;
    f32x4 acc[4][4] = {};
    for (int kt = 0; kt < KT; ++kt) {
        bf16x8 a[4], b[4];
#pragma unroll
        for (int i = 0; i < 4; ++i)
            a[i] = *(const bf16x8*)(Af + (((size_t)(mtb + i) * KT + kt) * 64 + lane) * 8);
#pragma unroll
        for (int j = 0; j < 4; ++j)
            b[j] = *(const bf16x8*)(Bf + (((size_t)(ntb + j) * KT + kt) * 64 + lane) * 8);
#pragma unroll
        for (int i = 0; i < 4; ++i)
#pragma unroll
            for (int j = 0; j < 4; ++j)
                acc[i][j] = __builtin_amdgcn_mfma_f32_16x16x32_bf16(a[i], b[j], acc[i][j], 0, 0, 0);
    }
    int c0 = lane & 15, r0 = (lane >> 4) * 4;
#pragma unroll
    for (int i = 0; i < 4; ++i) {
        int Rbase = (mtb + i) * 16 + r0;
        int lr0 = Rbase % NN;
#pragma unroll
        for (int r = 0; r < 4; ++r) {
            int R = Rbase + r;
            int lr = lr0 + r; if (lr >= NN) lr -= NN;
            char* rowp = xlr + (size_t)R * 1024;
            int sw = (lr & 7) << 4;
#pragma unroll
            for (int j = 0; j < 4; ++j) {
                int col = (ntb + j) * 16 + c0;
                *(bf16*)(rowp + ((col * 2) ^ sw)) = (bf16)acc[i][j][r];
            }
        }
    }
}

// ============ K3: edge phase layer 1 (per graph) ============
__global__ __launch_bounds__(512, 4) void k_edge1(const char* __restrict__ xlrG,
                                                  bf16* __restrict__ h1f,
                                                  const float* __restrict__ att1,
                                                  const float* __restrict__ g1b,
                                                  const int* __restrict__ csr) {
    __shared__ __align__(16) char X[NN * 1024];
    __shared__ float sc[NE * 4], srden[NN * 4], attS[256], bS[256];
    __shared__ int srcS[NE], dstS[NE], ieOff[50], ieId[NE], ieSrc[NE];

    int tid = threadIdx.x, g = blockIdx.x;
    const char* srcp = xlrG + (size_t)g * (NN * 1024);
    for (int off = tid * 16; off < NN * 1024; off += 512 * 16)
        *(uint4*)(X + off) = *(const uint4*)(srcp + off);
    for (int i = tid; i < 256; i += 512) { attS[i] = att1[i]; bS[i] = g1b[i]; }
    for (int i = tid; i < NE; i += 512) {
        srcS[i] = csr[0]; // placeholder avoided below
    }
    // proper staging (edge_index lives in csr-adjacent? no: stage from csr arrays)
    for (int i = tid; i < NE; i += 512) { ieId[i] = csr[50 + i]; ieSrc[i] = csr[50 + NE + i]; }
    if (tid < 50) ieOff[tid] = csr[tid];
    __syncthreads();
    // rebuild src/dst from csr: dst of in-edge j is the node n owning j; src = ieSrc.
    for (int n = tid; n < NN; n += 512)
        for (int j = ieOff[n]; j < ieOff[n + 1]; ++j) { dstS[ieId[j]] = n; srcS[ieId[j]] = ieSrc[j]; }
    __syncthreads();

    // ---- scores: thread per (h,e) ----
    int rot = tid & 7;
    for (int task = tid; task < NE * 4; task += 512) {
        int h = task / NE, e = task - h * NE;
        int s = srcS[e], d = dstS[e];
        int sws = (s & 7) << 4, swd = (d & 7) << 4;
        const char* ps = X + s * 1024;
        const char* pd = X + d * 1024;
        float p = 0.f;
#pragma unroll
        for (int i = 0; i < 8; ++i) {
            int cc = ((i + rot) & 7) * 8;
            bf16x8 xl = *(const bf16x8*)(ps + (((h * 64 + cc) * 2) ^ sws));
            bf16x8 xr = *(const bf16x8*)(pd + (((256 + h * 64 + cc) * 2) ^ swd));
            const float* at = attS + h * 64 + cc;
#pragma unroll
            for (int q = 0; q < 8; ++q) {
                float v = (float)xl[q] + (float)xr[q];
                v = fmaxf(v, 0.f) + 0.2f * fminf(v, 0.f);
                p += at[q] * v;
            }
        }
        sc[e * 4 + h] = p;
    }
    __syncthreads();
    // ---- softmax stats with exp-writeback ----
    for (int t = tid; t < NN * 4; t += 512) {
        int n = t >> 2, h = t & 3;
        float m = -1e30f;
        for (int j = ieOff[n]; j < ieOff[n + 1]; ++j) m = fmaxf(m, sc[ieId[j] * 4 + h]);
        float den = 0.f;
        for (int j = ieOff[n]; j < ieOff[n + 1]; ++j) {
            int idx = ieId[j] * 4 + h;
            float ex = __expf(sc[idx] - m);
            sc[idx] = ex; den += ex;
        }
        srden[t] = 1.f / den;
    }
    __syncthreads();
    for (int t = tid; t < NE * 4; t += 512) {
        int e = t >> 2, h = t & 3;
        sc[t] = sc[t] * srden[dstS[e] * 4 + h];
    }
    __syncthreads();
    // ---- aggregate + bias + ELU -> h1 fragments ----
    int gbase = g * NN;
    for (int task = tid; task < NN * 32; task += 512) {
        int n = task >> 5, cb = task & 31;
        int ch0 = cb * 8, hh = cb >> 3;
        float a8[8] = {};
        for (int j = ieOff[n]; j < ieOff[n + 1]; ++j) {
            float al = sc[ieId[j] * 4 + hh];
            int s = ieSrc[j];
            bf16x8 xv = *(const bf16x8*)(X + s * 1024 + ((ch0 * 2) ^ ((s & 7) << 4)));
#pragma unroll
            for (int q = 0; q < 8; ++q) a8[q] += al * (float)xv[q];
        }
        int Rl = gbase + n;
        bf16x8 o;
#pragma unroll
        for (int q = 0; q < 8; ++q) {
            float v = a8[q] + bS[ch0 + q];
            v = v > 0.f ? v : (__expf(v) - 1.f);
            o[q] = (bf16)v;
        }
        size_t addr = (((size_t)(Rl >> 4) * 8 + (ch0 >> 5)) * 64 + ((ch0 >> 3) & 3) * 16 + (Rl & 15)) * 8;
        *(bf16x8*)(h1f + addr) = o;
    }
}

// ============ K4: edge phase layer 2 + pool + FC (per graph) ============
static __device__ __forceinline__ float waveReduceSum(float v) {
#pragma unroll
    for (int m = 32; m > 0; m >>= 1) v += __shfl_xor(v, m, 64);
    return v;
}

__global__ __launch_bounds__(512, 4) void k_edge2(const char* __restrict__ xlrG,
                                                  const float* __restrict__ pooledN,
                                                  const float* __restrict__ att2,
                                                  const float* __restrict__ g2b,
                                                  const float* __restrict__ fcw,
                                                  const float* __restrict__ fcb,
                                                  const int* __restrict__ csr,
                                                  int graph_base,
                                                  float* __restrict__ out) {
    __shared__ __align__(16) char X[NN * 1024];
    __shared__ float sc2[NE * 2], scE[NE], srden[NN];
    __shared__ float attS[256], b2S[256], pA[256], pB[256], pool[288], fcwS[282 * 5];
    __shared__ int srcS[NE], dstS[NE], ieOff[50], ieId[NE];

    int tid = threadIdx.x, g = blockIdx.x;
    const char* srcp = xlrG + (size_t)g * (NN * 1024);
    for (int off = tid * 16; off < NN * 1024; off += 512 * 16)
        *(uint4*)(X + off) = *(const uint4*)(srcp + off);
    for (int i = tid; i < 256; i += 512) { attS[i] = att2[i]; b2S[i] = g2b[i]; }
    for (int i = tid; i < NE; i += 512) { ieId[i] = csr[50 + i]; }
    for (int i = tid; i < 282 * 5; i += 512) fcwS[i] = fcw[i];
    if (tid < 50) ieOff[tid] = csr[tid];
    __syncthreads();
    for (int n = tid; n < NN; n += 512)
        for (int j = ieOff[n]; j < ieOff[n + 1]; ++j) { dstS[ieId[j]] = n; srcS[ieId[j]] = csr[50 + NE + j]; }
    __syncthreads();

    // ---- scores: thread per (e,half) over 128 ch each ----
    int rot = tid & 7;
    for (int task = tid; task < NE * 2; task += 512) {
        int e = task >> 1, half = task & 1;
        int s = srcS[e], d = dstS[e];
        int sws = (s & 7) << 4, swd = (d & 7) << 4;
        const char* ps = X + s * 1024;
        const char* pd = X + d * 1024;
        float p = 0.f;
#pragma unroll
        for (int i = 0; i < 16; ++i) {
            int cc = half * 128 + (((i + rot) & 15)) * 8;
            bf16x8 xl = *(const bf16x8*)(ps + ((cc * 2) ^ sws));
            bf16x8 xr = *(const bf16x8*)(pd + (((256 + cc) * 2) ^ swd));
            const float* at = attS + cc;
#pragma unroll
            for (int q = 0; q < 8; ++q) {
                float v = (float)xl[q] + (float)xr[q];
                v = fmaxf(v, 0.f) + 0.2f * fminf(v, 0.f);
                p += at[q] * v;
            }
        }
        sc2[task] = p;
    }
    __syncthreads();
    for (int e = tid; e < NE; e += 512) scE[e] = sc2[2 * e] + sc2[2 * e + 1];
    __syncthreads();
    for (int n = tid; n < NN; n += 512) {
        float m = -1e30f;
        for (int j = ieOff[n]; j < ieOff[n + 1]; ++j) m = fmaxf(m, scE[ieId[j]]);
        float den = 0.f;
        for (int j = ieOff[n]; j < ieOff[n + 1]; ++j) {
            float ex = __expf(scE[ieId[j]] - m);
            scE[ieId[j]] = ex; den += ex;
        }
        srden[n] = 1.f / den;
    }
    __syncthreads();
    for (int e = tid; e < NE; e += 512) scE[e] = scE[e] * srden[dstS[e]];
    __syncthreads();

    // ---- pooled g: thread per (ch, half-edge-range) ----
    {
        int ch = tid & 255, half = tid >> 8;
        int e0 = half ? 181 : 0, e1 = half ? NE : 181;
        float acc = 0.f;
        for (int e = e0; e < e1; ++e) {
            int s = srcS[e];
            float v = (float)*(const bf16*)(X + s * 1024 + ((ch * 2) ^ ((s & 7) << 4)));
            acc += scE[e] * v;
        }
        (half ? pB : pA)[ch] = acc;
    }
    __syncthreads();
    if (tid < ND) pool[tid] = pooledN[(size_t)(graph_base + g) * ND + tid] * (1.f / NN);
    else if (tid >= 32 && tid < 32 + HID) {
        int ch = tid - 32;
        pool[ND + ch] = (pA[ch] + pB[ch]) * (1.f / NN) + b2S[ch];
    }
    __syncthreads();
    int w = tid >> 6, lane = tid & 63;
    if (w < 5) {
        float a = 0.f;
        for (int d = lane; d < ND + HID; d += 64) a += pool[d] * fcwS[d * 5 + w];
        a = waveReduceSum(a);
        if (lane == 0) out[(size_t)(graph_base + g) * 5 + w] = a + fcb[w];
    }
}

// ============ launch ============
extern "C" void kernel_launch(void* const* d_in, const int* in_sizes, int n_in,
                              void* d_out, int out_size, void* d_ws, size_t ws_size,
                              hipStream_t stream) {
    const float* x   = (const float*)d_in[0];
    const float* tw  = (const float*)d_in[1];
    const float* tb  = (const float*)d_in[2];
    const float* wl1 = (const float*)d_in[3];
    const float* wr1 = (const float*)d_in[4];
    const float* at1 = (const float*)d_in[5];
    const float* b1  = (const float*)d_in[6];
    const float* wl2 = (const float*)d_in[7];
    const float* wr2 = (const float*)d_in[8];
    const float* at2 = (const float*)d_in[9];
    const float* b2  = (const float*)d_in[10];
    const float* fcw = (const float*)d_in[11];
    const float* fcb = (const float*)d_in[12];
    const int*   ei  = (const int*)d_in[13];
    float* out = (float*)d_out;

    char* ws = (char*)d_ws;
    bf16*  xp   = (bf16*)(ws + OFF_XPACK);
    bf16*  wp   = (bf16*)(ws + OFF_WPACK);
    bf16*  b1p  = (bf16*)(ws + OFF_B1);
    bf16*  b2p  = (bf16*)(ws + OFF_B2);
    bf16*  A1   = (bf16*)(ws + OFF_A1);
    float* pN   = (float*)(ws + OFF_PN);
    int*   csr  = (int*)(ws + OFF_CSR);

    // pick chunk size C (graphs per chunk) to fit ws; C*49/16 must be mult of 8
    int C = 128;
    for (int cand : {2048, 1024, 512, 256, 128}) {
        if (OFF_CHUNK + (size_t)cand * (50176 + 25088) <= ws_size) { C = cand; break; }
    }
    char* xlr = ws + OFF_CHUNK;                       // C*50176 bytes
    bf16* h1f = (bf16*)(ws + OFF_CHUNK + (size_t)C * 50176);  // C*25088*2 bytes
    int nchunks = BATCH / C;
    int MtC = C * NN / 16;

    hipMemsetAsync(A1, 0, SZ_A1, stream);   // zero K-pad of layer-1 A fragments
    hipMemsetAsync(pN, 0, SZ_PN, stream);   // pooled-node accumulators

    k_pack_x<<<dim3(MT_X * KT_X * 64 / 256), dim3(256), 0, stream>>>(x, xp);
    k_pack_w<<<dim3(NT_X * KT_X * 64 / 256), dim3(256), 0, stream>>>(tw, wp);
    k_pack_g1<<<dim3(8), dim3(256), 0, stream>>>(wl1, wr1, b1p);
    k_pack_g2<<<dim3(64), dim3(256), 0, stream>>>(wl2, wr2, b2p);
    k_csr<<<dim3(1), dim3(64), 0, stream>>>(ei, csr);
    k_gemm_node<<<dim3(64, 10), dim3(256), 0, stream>>>(xp, wp, tb, A1, pN);

    for (int c = 0; c < nchunks; ++c) {
        const bf16* A1c = A1 + (size_t)c * MtC * 512;
        k_gemm_gat<1><<<dim3(MtC / 8, 4), dim3(256), 0, stream>>>(A1c, b1p, xlr);
        k_edge1<<<dim3(C), dim3(512), 0, stream>>>(xlr, h1f, at1, b1, csr);
        k_gemm_gat<8><<<dim3(MtC / 8, 4), dim3(256), 0, stream>>>(h1f, b2p, xlr);
        k_edge2<<<dim3(C), dim3(512), 0, stream>>>(xlr, pN, at2, b2, fcw, fcb, csr,
                                                   c * C, out);
    }
}

// Round 3
// 1024.333 us; speedup vs baseline: 3.4211x; 1.2996x over previous
//
#include <hip/hip_runtime.h>
#include <hip/hip_bf16.h>

typedef __bf16 bf16;
typedef __attribute__((ext_vector_type(8))) __bf16 bf16x8;
typedef __attribute__((ext_vector_type(4))) float f32x4;

constexpr int BATCH = 8192, NN = 49, ND = 26, NOUT = 1274, FD = 1280;
constexpr int HID = 256, NE = 361, HEADS = 4;
constexpr int KT_X = 40;   // 1280/32 K-tiles (transform)
constexpr int MT_X = 512;  // 8192/16 M-tiles
constexpr int NT_X = 80;   // 1280/16 N-tiles (1274 padded to 1280)

// ---- workspace layout (bytes) ----
constexpr size_t OFF_XPACK = 0;
constexpr size_t SZ_XPACK  = (size_t)MT_X * KT_X * 512 * 2;      // 20,971,520
constexpr size_t OFF_WPACK = OFF_XPACK + SZ_XPACK;
constexpr size_t SZ_WPACK  = (size_t)NT_X * KT_X * 512 * 2;      // 3,276,800
constexpr size_t OFF_B1    = OFF_WPACK + SZ_WPACK;
constexpr size_t SZ_B1     = (size_t)32 * 512 * 2;               // 32 KB
constexpr size_t OFF_B2    = OFF_B1 + SZ_B1;
constexpr size_t SZ_B2     = (size_t)32 * 8 * 512 * 2;           // 256 KB
constexpr size_t OFF_A1    = OFF_B2 + SZ_B2;
constexpr size_t SZ_A1     = (size_t)(BATCH * NN / 16) * 512 * 2; // 25,690,112
constexpr size_t OFF_PN    = OFF_A1 + SZ_A1;
constexpr size_t SZ_PN     = (size_t)BATCH * ND * 4;             // 851,968
constexpr size_t OFF_CSR   = OFF_PN + SZ_PN;
constexpr size_t SZ_CSR    = 8192;
constexpr size_t OFF_CHUNK = OFF_CSR + SZ_CSR;

// csr int layout: [0..49] in-off | [50..410] in-edge id | [411..771] in-edge src
//                 [772..821] out-off | [822..1182] out-edge id

// ============ K0a: pack x [8192][1280] f32 -> A-fragments bf16 ============
__global__ __launch_bounds__(256) void k_pack_x(const float* __restrict__ x,
                                                bf16* __restrict__ xp) {
    int g = blockIdx.x * 256 + threadIdx.x;
    int lane = g & 63, frag = g >> 6;
    int mt = frag / KT_X, kt = frag - mt * KT_X;
    int row = mt * 16 + (lane & 15);
    int k0  = kt * 32 + (lane >> 4) * 8;
    const float* src = x + (size_t)row * FD + k0;
    bf16x8 v;
#pragma unroll
    for (int j = 0; j < 8; ++j) v[j] = (bf16)src[j];
    *(bf16x8*)(xp + ((size_t)frag * 64 + lane) * 8) = v;
}

// ============ K0b: pack transform_w [1280][1274] -> B-fragments ============
__global__ __launch_bounds__(256) void k_pack_w(const float* __restrict__ w,
                                                bf16* __restrict__ wp) {
    int g = blockIdx.x * 256 + threadIdx.x;
    int lane = g & 63, frag = g >> 6;
    int nt = frag / KT_X, kt = frag - nt * KT_X;
    int col = nt * 16 + (lane & 15);
    int k0  = kt * 32 + (lane >> 4) * 8;
    bf16x8 v;
#pragma unroll
    for (int j = 0; j < 8; ++j)
        v[j] = (col < NOUT) ? (bf16)w[(size_t)(k0 + j) * NOUT + col] : (bf16)0.f;
    *(bf16x8*)(wp + ((size_t)frag * 64 + lane) * 8) = v;
}

// ============ K0c: pack g1 (wl|wr) [26k pad32 x 512n] -> B-fragments ========
__global__ __launch_bounds__(256) void k_pack_g1(const float* __restrict__ wl,
                                                 const float* __restrict__ wr,
                                                 bf16* __restrict__ bp) {
    int g = blockIdx.x * 256 + threadIdx.x;    // < 32*64
    int lane = g & 63, nt = g >> 6;
    int n  = nt * 16 + (lane & 15);
    int k0 = (lane >> 4) * 8;
    bf16x8 v;
#pragma unroll
    for (int j = 0; j < 8; ++j) {
        int k = k0 + j;
        float f = 0.f;
        if (k < ND) f = (n < HID) ? wl[k * HID + n] : wr[k * HID + (n - HID)];
        v[j] = (bf16)f;
    }
    *(bf16x8*)(bp + ((size_t)nt * 64 + lane) * 8) = v;
}

// ============ K0d: pack g2 (wl|wr) [256k x 512n] -> B-fragments ============
__global__ __launch_bounds__(256) void k_pack_g2(const float* __restrict__ wl,
                                                 const float* __restrict__ wr,
                                                 bf16* __restrict__ bp) {
    int g = blockIdx.x * 256 + threadIdx.x;    // < 256*64
    int lane = g & 63, frag = g >> 6;          // frag = nt*8+kt
    int nt = frag >> 3, kt = frag & 7;
    int n  = nt * 16 + (lane & 15);
    int k0 = kt * 32 + (lane >> 4) * 8;
    bf16x8 v;
#pragma unroll
    for (int j = 0; j < 8; ++j) {
        int k = k0 + j;
        float f = (n < HID) ? wl[k * HID + n] : wr[k * HID + (n - HID)];
        v[j] = (bf16)f;
    }
    *(bf16x8*)(bp + ((size_t)frag * 64 + lane) * 8) = v;
}

// ============ K0e: build in/out CSR (parallel, deterministic) ============
__global__ __launch_bounds__(128) void k_csr_par(const int* __restrict__ ei,
                                                 int* __restrict__ csr) {
    __shared__ int es[NE], ed[NE], cnt[NN], ocnt[NN], off[NN + 1], ooff[NN + 1];
    int tid = threadIdx.x;
    if (tid < NN) { cnt[tid] = 0; ocnt[tid] = 0; }
    for (int e = tid; e < NE; e += 128) { es[e] = ei[e]; ed[e] = ei[NE + e]; }
    __syncthreads();
    for (int e = tid; e < NE; e += 128) {
        atomicAdd(&cnt[ed[e]], 1);
        atomicAdd(&ocnt[es[e]], 1);
    }
    __syncthreads();
    if (tid == 0) {
        off[0] = 0; ooff[0] = 0;
        for (int n = 0; n < NN; ++n) {
            off[n + 1] = off[n] + cnt[n];
            ooff[n + 1] = ooff[n] + ocnt[n];
        }
    }
    __syncthreads();
    if (tid < NN) {                       // deterministic in-edge scatter
        int p = off[tid];
        for (int e = 0; e < NE; ++e)
            if (ed[e] == tid) { csr[50 + p] = e; csr[411 + p] = es[e]; ++p; }
    } else if (tid >= 64 && tid < 64 + NN) {  // deterministic out-edge scatter
        int n = tid - 64;
        int p = ooff[n];
        for (int e = 0; e < NE; ++e)
            if (es[e] == n) { csr[822 + p] = e; ++p; }
    }
    if (tid < 50) { csr[tid] = off[tid]; csr[772 + tid] = ooff[tid]; }
}

// ============ K1: transform GEMM -> A1 fragments (bf16) + pooled-node ======
__global__ __launch_bounds__(256) void k_gemm_node(const bf16* __restrict__ xp,
                                                   const bf16* __restrict__ wp,
                                                   const float* __restrict__ tb,
                                                   bf16* __restrict__ A1,
                                                   float* __restrict__ pooledN) {
    int tid = threadIdx.x, lane = tid & 63, w = tid >> 6;
    int mtb = blockIdx.x * 8 + (w >> 1) * 4;
    int ntb = blockIdx.y * 8 + (w & 1) * 4;
    f32x4 acc[4][4] = {};
    for (int kt = 0; kt < KT_X; ++kt) {
        bf16x8 a[4], b[4];
#pragma unroll
        for (int i = 0; i < 4; ++i)
            a[i] = *(const bf16x8*)(xp + (((size_t)(mtb + i) * KT_X + kt) * 64 + lane) * 8);
#pragma unroll
        for (int j = 0; j < 4; ++j)
            b[j] = *(const bf16x8*)(wp + (((size_t)(ntb + j) * KT_X + kt) * 64 + lane) * 8);
#pragma unroll
        for (int i = 0; i < 4; ++i)
#pragma unroll
            for (int j = 0; j < 4; ++j)
                acc[i][j] = __builtin_amdgcn_mfma_f32_16x16x32_bf16(a[i], b[j], acc[i][j], 0, 0, 0);
    }
    int c0 = lane & 15, r0 = (lane >> 4) * 4;
#pragma unroll
    for (int j = 0; j < 4; ++j) {
        int col = (ntb + j) * 16 + c0;
        if (col >= NOUT) continue;
        float bias = tb[col];
        int n = col / 26, d = col - n * 26;
#pragma unroll
        for (int i = 0; i < 4; ++i) {
            int rowb = (mtb + i) * 16 + r0;
#pragma unroll
            for (int r = 0; r < 4; ++r) {
                int brow = rowb + r;                  // batch index
                float val = acc[i][j][r] + bias;
                int R = brow * NN + n;                // global node row
                A1[(((size_t)(R >> 4)) * 64 + ((d >> 3) << 4) + (R & 15)) * 8 + (d & 7)] = (bf16)val;
                atomicAdd(&pooledN[brow * ND + d], val);
            }
        }
    }
}

// ============ K2: GAT GEMM (pre-packed frags -> swizzled row-major bf16) ===
template<int KT>
__global__ __launch_bounds__(256) void k_gemm_gat(const bf16* __restrict__ Af,
                                                  const bf16* __restrict__ Bf,
                                                  char* __restrict__ xlr) {
    int tid = threadIdx.x, lane = tid & 63, w = tid >> 6;
    int mtb = blockIdx.x * 8 + (w >> 1) * 4;
    int ntb = blockIdx.y * 8 + (w & 1) * 4;
    f32x4 acc[4][4] = {};
    for (int kt = 0; kt < KT; ++kt) {
        bf16x8 a[4], b[4];
#pragma unroll
        for (int i = 0; i < 4; ++i)
            a[i] = *(const bf16x8*)(Af + (((size_t)(mtb + i) * KT + kt) * 64 + lane) * 8);
#pragma unroll
        for (int j = 0; j < 4; ++j)
            b[j] = *(const bf16x8*)(Bf + (((size_t)(ntb + j) * KT + kt) * 64 + lane) * 8);
#pragma unroll
        for (int i = 0; i < 4; ++i)
#pragma unroll
            for (int j = 0; j < 4; ++j)
                acc[i][j] = __builtin_amdgcn_mfma_f32_16x16x32_bf16(a[i], b[j], acc[i][j], 0, 0, 0);
    }
    int c0 = lane & 15, r0 = (lane >> 4) * 4;
#pragma unroll
    for (int i = 0; i < 4; ++i) {
        int Rbase = (mtb + i) * 16 + r0;
        int lr0 = Rbase % NN;
#pragma unroll
        for (int r = 0; r < 4; ++r) {
            int R = Rbase + r;
            int lr = lr0 + r; if (lr >= NN) lr -= NN;
            char* rowp = xlr + (size_t)R * 1024;
            int sw = (lr & 7) << 4;
#pragma unroll
            for (int j = 0; j < 4; ++j) {
                int col = (ntb + j) * 16 + c0;
                *(bf16*)(rowp + ((col * 2) ^ sw)) = (bf16)acc[i][j][r];
            }
        }
    }
}

// ============ K3: edge phase layer 1 (per graph) ============
__global__ __launch_bounds__(512, 4) void k_edge1(const char* __restrict__ xlrG,
                                                  bf16* __restrict__ h1f,
                                                  const float* __restrict__ att1,
                                                  const float* __restrict__ g1b,
                                                  const int* __restrict__ ei,
                                                  const int* __restrict__ csr) {
    __shared__ __align__(16) char X[NN * 1024];
    __shared__ __align__(16) float attS[256];
    __shared__ float sc[NE * 4], srden[NN * 4], bS[256];
    __shared__ int srcS[NE], dstS[NE], ieOff[50], ieId[NE], ieSrc[NE];

    int tid = threadIdx.x, g = blockIdx.x;
    const char* srcp = xlrG + (size_t)g * (NN * 1024);
    for (int off = tid * 16; off < NN * 1024; off += 512 * 16)
        *(uint4*)(X + off) = *(const uint4*)(srcp + off);
    for (int i = tid; i < 256; i += 512) { attS[i] = att1[i]; bS[i] = g1b[i]; }
    for (int i = tid; i < NE; i += 512) {
        srcS[i] = ei[i]; dstS[i] = ei[NE + i];
        ieId[i] = csr[50 + i]; ieSrc[i] = csr[411 + i];
    }
    if (tid < 50) ieOff[tid] = csr[tid];
    __syncthreads();

    // ---- scores: thread per (h,e) ----
    int rot = tid & 7;
    for (int task = tid; task < NE * 4; task += 512) {
        int h = task / NE, e = task - h * NE;
        int s = srcS[e], d = dstS[e];
        int sws = (s & 7) << 4, swd = (d & 7) << 4;
        const char* ps = X + s * 1024;
        const char* pd = X + d * 1024;
        float p = 0.f;
#pragma unroll
        for (int i = 0; i < 8; ++i) {
            int cc = ((i + rot) & 7) * 8;
            bf16x8 xl = *(const bf16x8*)(ps + (((h * 64 + cc) * 2) ^ sws));
            bf16x8 xr = *(const bf16x8*)(pd + (((256 + h * 64 + cc) * 2) ^ swd));
            float4 a0 = *(const float4*)(attS + h * 64 + cc);
            float4 a1 = *(const float4*)(attS + h * 64 + cc + 4);
            const float aa[8] = {a0.x, a0.y, a0.z, a0.w, a1.x, a1.y, a1.z, a1.w};
#pragma unroll
            for (int q = 0; q < 8; ++q) {
                float v = (float)xl[q] + (float)xr[q];
                v = v > 0.f ? v : 0.2f * v;
                p = fmaf(aa[q], v, p);
            }
        }
        sc[e * 4 + h] = p;
    }
    __syncthreads();
    // ---- softmax stats with exp-writeback ----
    for (int t = tid; t < NN * 4; t += 512) {
        int n = t >> 2, h = t & 3;
        float m = -1e30f;
        for (int j = ieOff[n]; j < ieOff[n + 1]; ++j) m = fmaxf(m, sc[ieId[j] * 4 + h]);
        float den = 0.f;
        for (int j = ieOff[n]; j < ieOff[n + 1]; ++j) {
            int idx = ieId[j] * 4 + h;
            float ex = __expf(sc[idx] - m);
            sc[idx] = ex; den += ex;
        }
        srden[t] = 1.f / den;
    }
    __syncthreads();
    // ---- aggregate (srden hoisted) + bias + ELU -> h1 fragments ----
    int gbase = g * NN;
    for (int task = tid; task < NN * 32; task += 512) {
        int n = task >> 5, cb = task & 31;
        int ch0 = cb * 8, hh = cb >> 3;
        float a8[8] = {};
        int j0 = ieOff[n], j1 = ieOff[n + 1];
        for (int j = j0; j < j1; ++j) {
            float al = sc[ieId[j] * 4 + hh];
            int s = ieSrc[j];
            bf16x8 xv = *(const bf16x8*)(X + s * 1024 + ((ch0 * 2) ^ ((s & 7) << 4)));
#pragma unroll
            for (int q = 0; q < 8; ++q) a8[q] = fmaf(al, (float)xv[q], a8[q]);
        }
        float rs = srden[n * 4 + hh];
        int Rl = gbase + n;
        bf16x8 o;
#pragma unroll
        for (int q = 0; q < 8; ++q) {
            float v = fmaf(a8[q], rs, bS[ch0 + q]);
            v = v > 0.f ? v : (__expf(v) - 1.f);
            o[q] = (bf16)v;
        }
        size_t addr = (((size_t)(Rl >> 4) * 8 + (ch0 >> 5)) * 64 + ((ch0 >> 3) & 3) * 16 + (Rl & 15)) * 8;
        *(bf16x8*)(h1f + addr) = o;
    }
}

// ============ K4: edge phase layer 2 + pool + FC (per graph) ============
static __device__ __forceinline__ float waveReduceSum(float v) {
#pragma unroll
    for (int m = 32; m > 0; m >>= 1) v += __shfl_xor(v, m, 64);
    return v;
}

__global__ __launch_bounds__(512, 4) void k_edge2(const char* __restrict__ xlrG,
                                                  const float* __restrict__ pooledN,
                                                  const float* __restrict__ att2,
                                                  const float* __restrict__ g2b,
                                                  const float* __restrict__ fcw,
                                                  const float* __restrict__ fcb,
                                                  const int* __restrict__ ei,
                                                  const int* __restrict__ csr,
                                                  int graph_base,
                                                  float* __restrict__ out) {
    __shared__ __align__(16) char X[NN * 1024];
    __shared__ __align__(16) float attS[256];
    __shared__ float sc2[NE * 2], scE[NE], srdenN[NN], smaxN[NN], wS[NN];
    __shared__ float b2S[256], pA[256], pB[256], pool[288], fcwS[282 * 5];
    __shared__ int srcS[NE], dstS[NE], ieOff[50], ieId[NE], oOff[50], oId[NE];

    int tid = threadIdx.x, g = blockIdx.x;
    const char* srcp = xlrG + (size_t)g * (NN * 1024);
    for (int off = tid * 16; off < NN * 1024; off += 512 * 16)
        *(uint4*)(X + off) = *(const uint4*)(srcp + off);
    for (int i = tid; i < 256; i += 512) { attS[i] = att2[i]; b2S[i] = g2b[i]; }
    for (int i = tid; i < NE; i += 512) {
        srcS[i] = ei[i]; dstS[i] = ei[NE + i];
        ieId[i] = csr[50 + i]; oId[i] = csr[822 + i];
    }
    if (tid < 50) { ieOff[tid] = csr[tid]; oOff[tid] = csr[772 + tid]; }
    for (int i = tid; i < 282 * 5; i += 512) fcwS[i] = fcw[i];
    __syncthreads();

    // ---- scores: thread per (e,half) over 128 ch each ----
    int rot = tid & 7;
    for (int task = tid; task < NE * 2; task += 512) {
        int e = task >> 1, half = task & 1;
        int s = srcS[e], d = dstS[e];
        int sws = (s & 7) << 4, swd = (d & 7) << 4;
        const char* ps = X + s * 1024;
        const char* pd = X + d * 1024;
        float p = 0.f;
#pragma unroll
        for (int i = 0; i < 16; ++i) {
            int cc = half * 128 + (((i + rot) & 15)) * 8;
            bf16x8 xl = *(const bf16x8*)(ps + ((cc * 2) ^ sws));
            bf16x8 xr = *(const bf16x8*)(pd + (((256 + cc) * 2) ^ swd));
            float4 a0 = *(const float4*)(attS + cc);
            float4 a1 = *(const float4*)(attS + cc + 4);
            const float aa[8] = {a0.x, a0.y, a0.z, a0.w, a1.x, a1.y, a1.z, a1.w};
#pragma unroll
            for (int q = 0; q < 8; ++q) {
                float v = (float)xl[q] + (float)xr[q];
                v = v > 0.f ? v : 0.2f * v;
                p = fmaf(aa[q], v, p);
            }
        }
        sc2[task] = p;
    }
    __syncthreads();
    for (int e = tid; e < NE; e += 512) scE[e] = sc2[2 * e] + sc2[2 * e + 1];
    __syncthreads();
    // ---- softmax stats per node ----
    for (int n = tid; n < NN; n += 512) {
        float m = -1e30f;
        for (int j = ieOff[n]; j < ieOff[n + 1]; ++j) m = fmaxf(m, scE[ieId[j]]);
        float den = 0.f;
        for (int j = ieOff[n]; j < ieOff[n + 1]; ++j) den += __expf(scE[ieId[j]] - m);
        smaxN[n] = m; srdenN[n] = 1.f / den;
    }
    __syncthreads();
    // ---- out-node weights w_n = sum over out-edges of alpha (deterministic) ----
    for (int n = tid; n < NN; n += 512) {
        float wacc = 0.f;
        for (int j = oOff[n]; j < oOff[n + 1]; ++j) {
            int e = oId[j], d = dstS[e];
            wacc += __expf(scE[e] - smaxN[d]) * srdenN[d];
        }
        wS[n] = wacc;
    }
    __syncthreads();
    // ---- pooled g = sum_n wS[n] * xl2[n][ch]  (conflict-free contiguous reads) ----
    {
        int ch = tid & 255, half = tid >> 8;
        int n0 = half ? 25 : 0, n1 = half ? NN : 25;
        float acc = 0.f;
        for (int n = n0; n < n1; ++n) {
            float v = (float)*(const bf16*)(X + n * 1024 + ((ch * 2) ^ ((n & 7) << 4)));
            acc = fmaf(wS[n], v, acc);
        }
        (half ? pB : pA)[ch] = acc;
    }
    __syncthreads();
    if (tid < ND) pool[tid] = pooledN[(size_t)(graph_base + g) * ND + tid] * (1.f / NN);
    else if (tid >= 32 && tid < 32 + HID) {
        int ch = tid - 32;
        pool[ND + ch] = (pA[ch] + pB[ch]) * (1.f / NN) + b2S[ch];
    }
    __syncthreads();
    int w5 = tid >> 6, lane = tid & 63;
    if (w5 < 5) {
        float a = 0.f;
        for (int d = lane; d < ND + HID; d += 64) a = fmaf(pool[d], fcwS[d * 5 + w5], a);
        a = waveReduceSum(a);
        if (lane == 0) out[(size_t)(graph_base + g) * 5 + w5] = a + fcb[w5];
    }
}

// ============ launch ============
extern "C" void kernel_launch(void* const* d_in, const int* in_sizes, int n_in,
                              void* d_out, int out_size, void* d_ws, size_t ws_size,
                              hipStream_t stream) {
    const float* x   = (const float*)d_in[0];
    const float* tw  = (const float*)d_in[1];
    const float* tb  = (const float*)d_in[2];
    const float* wl1 = (const float*)d_in[3];
    const float* wr1 = (const float*)d_in[4];
    const float* at1 = (const float*)d_in[5];
    const float* b1  = (const float*)d_in[6];
    const float* wl2 = (const float*)d_in[7];
    const float* wr2 = (const float*)d_in[8];
    const float* at2 = (const float*)d_in[9];
    const float* b2  = (const float*)d_in[10];
    const float* fcw = (const float*)d_in[11];
    const float* fcb = (const float*)d_in[12];
    const int*   ei  = (const int*)d_in[13];
    float* out = (float*)d_out;

    char* ws = (char*)d_ws;
    bf16*  xp   = (bf16*)(ws + OFF_XPACK);
    bf16*  wp   = (bf16*)(ws + OFF_WPACK);
    bf16*  b1p  = (bf16*)(ws + OFF_B1);
    bf16*  b2p  = (bf16*)(ws + OFF_B2);
    bf16*  A1   = (bf16*)(ws + OFF_A1);
    float* pN   = (float*)(ws + OFF_PN);
    int*   csr  = (int*)(ws + OFF_CSR);

    // pick chunk size C (graphs per chunk) to fit ws; C multiple of 128
    int C = 128;
    for (int cand : {2048, 1024, 512, 256, 128}) {
        if (OFF_CHUNK + (size_t)cand * (50176 + 25088) <= ws_size) { C = cand; break; }
    }
    char* xlr = ws + OFF_CHUNK;                       // C*50176 bytes
    bf16* h1f = (bf16*)(ws + OFF_CHUNK + (size_t)C * 50176);  // C*25088*2 bytes
    int nchunks = BATCH / C;
    int MtC = C * NN / 16;

    hipMemsetAsync(A1, 0, SZ_A1, stream);   // zero K-pad of layer-1 A fragments
    hipMemsetAsync(pN, 0, SZ_PN, stream);   // pooled-node accumulators

    k_pack_x<<<dim3(MT_X * KT_X * 64 / 256), dim3(256), 0, stream>>>(x, xp);
    k_pack_w<<<dim3(NT_X * KT_X * 64 / 256), dim3(256), 0, stream>>>(tw, wp);
    k_pack_g1<<<dim3(8), dim3(256), 0, stream>>>(wl1, wr1, b1p);
    k_pack_g2<<<dim3(64), dim3(256), 0, stream>>>(wl2, wr2, b2p);
    k_csr_par<<<dim3(1), dim3(128), 0, stream>>>(ei, csr);
    k_gemm_node<<<dim3(64, 10), dim3(256), 0, stream>>>(xp, wp, tb, A1, pN);

    for (int c = 0; c < nchunks; ++c) {
        const bf16* A1c = A1 + (size_t)c * MtC * 512;
        k_gemm_gat<1><<<dim3(MtC / 8, 4), dim3(256), 0, stream>>>(A1c, b1p, xlr);
        k_edge1<<<dim3(C), dim3(512), 0, stream>>>(xlr, h1f, at1, b1, ei, csr);
        k_gemm_gat<8><<<dim3(MtC / 8, 4), dim3(256), 0, stream>>>(h1f, b2p, xlr);
        k_edge2<<<dim3(C), dim3(512), 0, stream>>>(xlr, pN, at2, b2, fcw, fcb, ei, csr,
                                                   c * C, out);
    }
}